// Round 2
// baseline (2857.349 us; speedup 1.0000x reference)
//
#include <hip/hip_runtime.h>

#define T_STEPS 512
#define BATCH   256
#define DIM     1024
#define NOUT    5
#define BH      (BATCH*DIM)
#define TB      (T_STEPS*BATCH)

typedef short s16x8 __attribute__((ext_vector_type(8)));
typedef float f32x4 __attribute__((ext_vector_type(4)));
typedef unsigned short u16;
typedef unsigned int   u32;

__device__ __forceinline__ u16 f2bf(float f) {
    union { float f; u32 u; } v; v.f = f;
    u32 r = v.u + 0x7FFFu + ((v.u >> 16) & 1u);   // RNE
    return (u16)(r >> 16);
}
__device__ __forceinline__ float bf2f(u16 u) {
    union { u32 u; float f; } v; v.u = ((u32)u) << 16;
    return v.f;
}
__device__ __forceinline__ s16x8 cvt8(float4 a, float4 b) {
    s16x8 v;
    v[0]=(short)f2bf(a.x); v[1]=(short)f2bf(a.y); v[2]=(short)f2bf(a.z); v[3]=(short)f2bf(a.w);
    v[4]=(short)f2bf(b.x); v[5]=(short)f2bf(b.y); v[6]=(short)f2bf(b.z); v[7]=(short)f2bf(b.w);
    return v;
}

// --- per-instruction coherent (LLC-level) memory ops: bypass L1+L2 (sc0 sc1).
__device__ __forceinline__ void ldg_cv16_issue(const u16* p, s16x8* dst) {
    asm volatile("global_load_dwordx4 %0, %1, off sc0 sc1"
                 : "=v"(*dst) : "v"(p) : "memory");
}
__device__ __forceinline__ void stg_cv8(u16* p, ushort4 v) {
    asm volatile("global_store_dwordx2 %0, %1, off sc0 sc1"
                 :: "v"(p), "v"(v) : "memory");
}
__device__ __forceinline__ void stg_cv4(u32* p, u32 v) {
    asm volatile("global_store_dword %0, %1, off sc0 sc1"
                 :: "v"(p), "v"(v) : "memory");
}
__device__ __forceinline__ void wait_vm0() {
    asm volatile("s_waitcnt vmcnt(0)" ::: "memory");
}

// ---------------------------------------------------------------- convert fp32 -> bf16 (W_in)
__global__ __launch_bounds__(256) void cvt_kernel(const float* __restrict__ src,
                                                  u16* __restrict__ dst, int n4) {
    int i = blockIdx.x * 256 + threadIdx.x;
    if (i < n4) {
        float4 x = ((const float4*)src)[i];
        ushort4 o;
        o.x = f2bf(x.x); o.y = f2bf(x.y); o.z = f2bf(x.z); o.w = f2bf(x.w);
        ((ushort4*)dst)[i] = o;
    }
}

// ---------------------------------------------------------------- convert fp32 -> bf16 (X, 8/thread)
__global__ __launch_bounds__(256) void cvt_x(const float* __restrict__ src,
                                             u16* __restrict__ dst, int n8) {
    int i = blockIdx.x * 256 + threadIdx.x;
    if (i < n8) {
        float4 a = ((const float4*)src)[2*i];
        float4 b = ((const float4*)src)[2*i + 1];
        *(s16x8*)&dst[(size_t)i*8] = cvt8(a, b);
    }
}

// ---------------------------------------------------------------- Phase 1 (pre-cvt path):
// E = Xb @ Wb^T + b_in, both operands bf16, both staged via global_load_lds
// with XOR-pre-swizzled SOURCE chunks (linear LDS dest, swizzled read).
__global__ __launch_bounds__(256, 2) void gemm_e_bf(
    const u16*   __restrict__ Xb,   // [131072][1024] bf16
    const u16*   __restrict__ Wb,   // [1024][1024] bf16 (row = out col, K contiguous)
    const float* __restrict__ b_in, // [1024]
    u16*         __restrict__ E)    // [131072][1024] bf16
{
    __shared__ u16 sA[128 * 64];
    __shared__ u16 sB[128 * 64];

    const int K = 1024;
    int tid  = threadIdx.x;
    int lane = tid & 63, wv = tid >> 6;
    int lm   = lane & 15, quad = lane >> 4;

    // XCD-team swizzle: all 8 bn-blocks of one bm share the A-tile via XCD L2.
    int bid = blockIdx.x;
    int xcd = bid & 7;
    int s   = bid >> 3;
    int bn  = s & 7;
    int bm  = (s >> 3) * 8 + xcd;

    int wm = wv >> 1, wn = wv & 1;

    float bias[4];
#pragma unroll
    for (int nt = 0; nt < 4; ++nt)
        bias[nt] = b_in[bn*128 + wn*64 + nt*16 + lm];

    f32x4 acc[4][4];
#pragma unroll
    for (int a = 0; a < 4; ++a)
#pragma unroll
        for (int b = 0; b < 4; ++b)
            acc[a][b] = (f32x4){0.f, 0.f, 0.f, 0.f};

    int colX  = (lane & 7) ^ (lane >> 3);   // source-chunk pre-swizzle
    int rowX0 = lane >> 3;

    for (int kk = 0; kk < K; kk += 64) {
#pragma unroll
        for (int i = 0; i < 4; ++i) {
            int q   = i*4 + wv;
            int row = q*8 + rowX0;
            const u16* gpB = Wb + (size_t)(bn*128 + row)*K + kk + colX*8;
            __builtin_amdgcn_global_load_lds(
                (const __attribute__((address_space(1))) void*)gpB,
                (__attribute__((address_space(3))) void*)(sB + q*512),
                16, 0, 0);
            const u16* gpA = Xb + (size_t)(bm*128 + row)*K + kk + colX*8;
            __builtin_amdgcn_global_load_lds(
                (const __attribute__((address_space(1))) void*)gpA,
                (__attribute__((address_space(3))) void*)(sA + q*512),
                16, 0, 0);
        }
        __syncthreads();   // compiler drains vmcnt before s_barrier
#pragma unroll
        for (int kc = 0; kc < 2; ++kc) {
            s16x8 af[4], bfr[4];
            int c8 = kc*4 + quad;
#pragma unroll
            for (int mt = 0; mt < 4; ++mt) {
                int row = wm*64 + mt*16 + lm;
                af[mt] = *(const s16x8*)&sA[row*64 + ((c8 ^ (row & 7)) * 8)];
            }
#pragma unroll
            for (int nt = 0; nt < 4; ++nt) {
                int row = wn*64 + nt*16 + lm;
                bfr[nt] = *(const s16x8*)&sB[row*64 + ((c8 ^ (row & 7)) * 8)];
            }
#pragma unroll
            for (int mt = 0; mt < 4; ++mt)
#pragma unroll
                for (int nt = 0; nt < 4; ++nt)
                    acc[mt][nt] = __builtin_amdgcn_mfma_f32_16x16x32_bf16(
                        af[mt], bfr[nt], acc[mt][nt], 0, 0, 0);
        }
        __syncthreads();
    }
#pragma unroll
    for (int mt = 0; mt < 4; ++mt)
#pragma unroll
        for (int nt = 0; nt < 4; ++nt)
#pragma unroll
            for (int i = 0; i < 4; ++i) {
                int row = bm*128 + wm*64 + mt*16 + quad*4 + i;
                int col = bn*128 + wn*64 + nt*16 + lm;
                E[(size_t)row*1024 + col] = f2bf(acc[mt][nt][i] + bias[nt]);
            }
}

// ---------------------------------------------------------------- Phase 1 fallback (fp32 X staged in-kernel)
#define PADA 88

__global__ __launch_bounds__(256, 2) void gemm_e(
    const float* __restrict__ X,
    const u16*   __restrict__ Wb,
    const float* __restrict__ b_in,
    u16*         __restrict__ E)
{
    __shared__ u16 sA[128 * PADA];
    __shared__ u16 sB[128 * 64];

    const int K = 1024;
    int tid  = threadIdx.x;
    int lane = tid & 63, wv = tid >> 6;
    int lm   = lane & 15, quad = lane >> 4;

    int bid = blockIdx.x;
    int xcd = bid & 7;
    int s   = bid >> 3;
    int bn  = s & 7;
    int bm  = (s >> 3) * 8 + xcd;

    int wm = wv >> 1, wn = wv & 1;

    float bias[4];
#pragma unroll
    for (int nt = 0; nt < 4; ++nt)
        bias[nt] = b_in[bn*128 + wn*64 + nt*16 + lm];

    f32x4 acc[4][4];
#pragma unroll
    for (int a = 0; a < 4; ++a)
#pragma unroll
        for (int b = 0; b < 4; ++b)
            acc[a][b] = (f32x4){0.f, 0.f, 0.f, 0.f};

    int colB  = (lane & 7) ^ (lane >> 3);
    int rowB0 = lane >> 3;

    for (int kk = 0; kk < K; kk += 64) {
#pragma unroll
        for (int i = 0; i < 4; ++i) {
            int q   = i*4 + wv;
            int row = q*8 + rowB0;
            const u16* gp = Wb + (size_t)(bn*128 + row)*K + kk + colB*8;
            __builtin_amdgcn_global_load_lds(
                (const __attribute__((address_space(1))) void*)gp,
                (__attribute__((address_space(3))) void*)(sB + q*512),
                16, 0, 0);
        }
#pragma unroll
        for (int p = 0; p < 4; ++p) {
            int row = (tid >> 3) + 32*p;
            int k8  = (tid & 7) * 8;
            const float* gp = X + (size_t)(bm*128 + row)*K + kk + k8;
            float4 x0 = ((const float4*)gp)[0];
            float4 x1 = ((const float4*)gp)[1];
            *(s16x8*)&sA[row*PADA + k8] = cvt8(x0, x1);
        }
        __syncthreads();
#pragma unroll
        for (int kc = 0; kc < 2; ++kc) {
            s16x8 af[4], bfr[4];
#pragma unroll
            for (int mt = 0; mt < 4; ++mt) {
                int row = wm*64 + mt*16 + lm;
                af[mt] = *(const s16x8*)&sA[row*PADA + kc*32 + quad*8];
            }
            int c8 = kc*4 + quad;
#pragma unroll
            for (int nt = 0; nt < 4; ++nt) {
                int row = wn*64 + nt*16 + lm;
                bfr[nt] = *(const s16x8*)&sB[row*64 + ((c8 ^ (row & 7)) * 8)];
            }
#pragma unroll
            for (int mt = 0; mt < 4; ++mt)
#pragma unroll
                for (int nt = 0; nt < 4; ++nt)
                    acc[mt][nt] = __builtin_amdgcn_mfma_f32_16x16x32_bf16(
                        af[mt], bfr[nt], acc[mt][nt], 0, 0, 0);
        }
        __syncthreads();
    }
#pragma unroll
    for (int mt = 0; mt < 4; ++mt)
#pragma unroll
        for (int nt = 0; nt < 4; ++nt)
#pragma unroll
            for (int i = 0; i < 4; ++i) {
                int row = bm*128 + wm*64 + mt*16 + quad*4 + i;
                int col = bn*128 + wn*64 + nt*16 + lm;
                E[(size_t)row*1024 + col] = f2bf(acc[mt][nt][i] + bias[nt]);
            }
}

// ---------------------------------------------------------------- Phase 2: recurrence
// 256 WGs = 16 row-groups x 16 col-groups. W_h persistent in VGPRs, K split
// over 4 waves. Per-WAVE sub-flags (4 per producer WG, one 64B line):
// producer wave publishes its 4 rows right after its own vmcnt(0) ack — no
// WG barrier on the producer->flag path. Consumer wave polls ONLY its 4
// K-quarter producers (4 cachelines/wave). WAR on double-buffered hbuf is
// safe: the mid-step __syncthreads joins all 4 waves, and the union of their
// poll sets = all 16 WGs >= t, so stores at step t happen-after every reader
// of the overwritten buffer finished step t-1. LDS reduce is double-buffered
// -> ONE barrier per step.
__global__ __launch_bounds__(256, 1) void rnn_phase2(
    const float* __restrict__ h0,   // [256][1024] fp32
    const float* __restrict__ Wh,   // [1024][1024] fp32 (row = out col)
    const float* __restrict__ bh,   // [1024]
    const u16*   __restrict__ E,    // [512][256][1024] bf16
    u16*         __restrict__ hbuf, // [2][256][1024] bf16
    u32*         __restrict__ flags,// [256 producers][16 u32 line]; sub-flags at +0,4,8,12
    float*       __restrict__ hidden_out) // [256][1024] fp32
{
    __shared__ float red[2][4][16][68];
    int tid  = threadIdx.x;
    int lane = tid & 63, wv = tid >> 6;
    int lm   = lane & 15, quad = lane >> 4;
    int r    = blockIdx.x >> 4, c = blockIdx.x & 15;

    // --- persistent W_h fragments (one-time load, fp32 -> bf16)
    s16x8 wf[4][8];
#pragma unroll
    for (int ct = 0; ct < 4; ++ct)
#pragma unroll
        for (int kc = 0; kc < 8; ++kc) {
            int n = c*64 + ct*16 + lm;
            int k = wv*256 + kc*32 + quad*8;
            const float* p = Wh + (size_t)n*1024 + k;
            float4 x0 = ((const float4*)p)[0];
            float4 x1 = ((const float4*)p)[1];
            wf[ct][kc] = cvt8(x0, x1);
        }

    int m  = tid >> 4;          // reduce-phase row 0..15
    int n4 = (tid & 15) * 4;    // reduce-phase col base (of 64)
    float4 bh4 = *(const float4*)&bh[c*64 + n4];
    int rowA = r*16 + lm;
    // consumer wave wv needs producers c' = wv*4 .. wv*4+3 (cols wv*256..+255),
    // all 4 sub-flags each: lane L -> producer wv*4+(L&3), sub (L>>2)&3.
    const u32* fpoll = flags + (size_t)(r*16 + wv*4 + (lane & 3))*16 + ((lane >> 2) & 3)*4;
    // producer wave wv owns rows 4*wv..4*wv+3 of this WG's tile.
    u32* fown = flags + (size_t)(r*16 + c)*16 + wv*4;

    for (int t = 0; t < T_STEPS; ++t) {
        if (t > 0) {
            u32 target = (u32)t;
            for (;;) {
                u32 v;
                asm volatile("global_load_dword %0, %1, off sc0 sc1"
                             : "=v"(v) : "v"(fpoll) : "memory");
                asm volatile("s_waitcnt vmcnt(0)" ::: "memory");
                if (__all(v >= target)) break;
                __builtin_amdgcn_s_sleep(1);
            }
        }

        // E[t] is race-free (phase-1 data): normal cached load; its latency
        // overlaps the af loads below (drained by the same vmcnt(0)).
        ushort4 e4 = *(const ushort4*)&E[(size_t)t*BH + (size_t)(r*16 + m)*1024 + c*64 + n4];

        // A fragments: h rows for this group, this wave's K quarter
        s16x8 af[8];
        if (t == 0) {
#pragma unroll
            for (int kc = 0; kc < 8; ++kc) {
                const float* p = h0 + (size_t)rowA*1024 + wv*256 + kc*32 + quad*8;
                float4 x0 = ((const float4*)p)[0];
                float4 x1 = ((const float4*)p)[1];
                af[kc] = cvt8(x0, x1);
            }
        } else {
            const u16* hb = hbuf + (size_t)(t & 1)*BH;
#pragma unroll
            for (int kc = 0; kc < 8; ++kc)
                ldg_cv16_issue(&hb[(size_t)rowA*1024 + wv*256 + kc*32 + quad*8], &af[kc]);
            asm volatile("s_waitcnt vmcnt(0)"
                         : "+v"(af[0]), "+v"(af[1]), "+v"(af[2]), "+v"(af[3]),
                           "+v"(af[4]), "+v"(af[5]), "+v"(af[6]), "+v"(af[7])
                         :: "memory");
        }

        f32x4 acc[4];
#pragma unroll
        for (int ct = 0; ct < 4; ++ct) acc[ct] = (f32x4){0.f, 0.f, 0.f, 0.f};
#pragma unroll
        for (int kc = 0; kc < 8; ++kc)
#pragma unroll
            for (int ct = 0; ct < 4; ++ct)
                acc[ct] = __builtin_amdgcn_mfma_f32_16x16x32_bf16(af[kc], wf[ct][kc], acc[ct], 0, 0, 0);

        // K-partial results -> LDS (double-buffered; D layout: row = quad*4+i, col = lm)
#pragma unroll
        for (int ct = 0; ct < 4; ++ct)
#pragma unroll
            for (int i = 0; i < 4; ++i)
                red[t & 1][wv][quad*4 + i][ct*16 + lm] = acc[ct][i];
        __syncthreads();   // the ONLY barrier per step

        // reduce 4 wave-partials + bias + e, sigmoid, store
        float4 p0 = *(const float4*)&red[t & 1][0][m][n4];
        float4 p1 = *(const float4*)&red[t & 1][1][m][n4];
        float4 p2 = *(const float4*)&red[t & 1][2][m][n4];
        float4 p3 = *(const float4*)&red[t & 1][3][m][n4];
        float4 s;
        s.x = p0.x + p1.x + p2.x + p3.x + bh4.x + bf2f(e4.x);
        s.y = p0.y + p1.y + p2.y + p3.y + bh4.y + bf2f(e4.y);
        s.z = p0.z + p1.z + p2.z + p3.z + bh4.z + bf2f(e4.z);
        s.w = p0.w + p1.w + p2.w + p3.w + bh4.w + bf2f(e4.w);
        float4 h;
        h.x = 1.f / (1.f + __expf(-s.x));
        h.y = 1.f / (1.f + __expf(-s.y));
        h.z = 1.f / (1.f + __expf(-s.z));
        h.w = 1.f / (1.f + __expf(-s.w));

        if (t < T_STEPS - 1) {
            ushort4 hb4;
            hb4.x = f2bf(h.x); hb4.y = f2bf(h.y); hb4.z = f2bf(h.z); hb4.w = f2bf(h.w);
            stg_cv8(&hbuf[(size_t)((t + 1) & 1)*BH + (size_t)(r*16 + m)*1024 + c*64 + n4], hb4);
        } else {
            *(float4*)&hidden_out[(size_t)(r*16 + m)*1024 + c*64 + n4] = h;
        }

        wait_vm0();   // this wave's h stores acked at the coherence point
        if (lane == 0 && t < T_STEPS - 1)
            stg_cv4(fown, (u32)(t + 1));   // per-wave sub-flag, fire-and-forget
    }
}

// ---------------------------------------------------------------- Phase 3: log_softmax(h W_o^T + b_o)
__global__ __launch_bounds__(64) void head_kernel(const float* __restrict__ h,
                                                  const float* __restrict__ Wo,
                                                  const float* __restrict__ bo,
                                                  float* __restrict__ out)
{
    int b = blockIdx.x, l = threadIdx.x;
    float a0 = 0.f, a1 = 0.f, a2 = 0.f, a3 = 0.f, a4 = 0.f;
    for (int k = l; k < DIM; k += 64) {
        float hv = h[b*DIM + k];
        a0 += hv * Wo[0*DIM + k];
        a1 += hv * Wo[1*DIM + k];
        a2 += hv * Wo[2*DIM + k];
        a3 += hv * Wo[3*DIM + k];
        a4 += hv * Wo[4*DIM + k];
    }
#pragma unroll
    for (int off = 32; off >= 1; off >>= 1) {
        a0 += __shfl_down(a0, off);
        a1 += __shfl_down(a1, off);
        a2 += __shfl_down(a2, off);
        a3 += __shfl_down(a3, off);
        a4 += __shfl_down(a4, off);
    }
    if (l == 0) {
        float v[5] = {a0 + bo[0], a1 + bo[1], a2 + bo[2], a3 + bo[3], a4 + bo[4]};
        float mx = v[0];
#pragma unroll
        for (int o = 1; o < 5; ++o) mx = fmaxf(mx, v[o]);
        float sum = 0.f;
#pragma unroll
        for (int o = 0; o < 5; ++o) sum += __expf(v[o] - mx);
        float lse = mx + __logf(sum);
#pragma unroll
        for (int o = 0; o < 5; ++o) out[b*NOUT + o] = v[o] - lse;
    }
}

// ---------------------------------------------------------------- launch
extern "C" void kernel_launch(void* const* d_in, const int* in_sizes, int n_in,
                              void* d_out, int out_size, void* d_ws, size_t ws_size,
                              hipStream_t stream)
{
    const float* X   = (const float*)d_in[0];
    const float* h0  = (const float*)d_in[1];
    const float* st  = (const float*)d_in[2];
    const float* Win = (const float*)d_in[3];
    const float* bin = (const float*)d_in[4];
    const float* Wh  = (const float*)d_in[5];
    const float* bhp = (const float*)d_in[6];
    const float* Wo  = (const float*)d_in[7];
    const float* bo  = (const float*)d_in[8];

    char*  ws      = (char*)d_ws;
    size_t off_hb  = 32768;
    size_t off_wb  = off_hb + (size_t)2*BH*2;
    size_t off_e   = off_wb + (size_t)DIM*DIM*2;
    size_t off_xb  = off_e + (size_t)TB*DIM*2;
    size_t need_bf = off_xb + (size_t)TB*DIM*2;

    u32* flags = (u32*)ws;
    u16* hbuf  = (u16*)(ws + off_hb);
    u16* Wbf   = (u16*)(ws + off_wb);
    u16* E     = (u16*)(ws + off_e);
    u16* Xbf   = (u16*)(ws + off_xb);

    float* out_lp = (float*)d_out;          // [256][5]
    float* out_h  = out_lp + BATCH*NOUT;    // [256][1024]
    float* out_st = out_h + BH;             // [256][1024]

    hipMemsetAsync(flags, 0, 32768, stream);
    cvt_kernel<<<(DIM*DIM/4 + 255)/256, 256, 0, stream>>>(Win, Wbf, DIM*DIM/4);

    if (ws_size >= need_bf) {
        // pre-convert X once (bit-identical RNE), then pure-DMA-staged GEMM
        cvt_x<<<(TB*DIM/8)/256, 256, 0, stream>>>(X, Xbf, TB*DIM/8);
        gemm_e_bf<<<(TB/128)*8, 256, 0, stream>>>(Xbf, Wbf, bin, E);
    } else {
        gemm_e<<<(TB/128)*8, 256, 0, stream>>>(X, Wbf, bin, E);
    }

    rnn_phase2<<<256, 256, 0, stream>>>(h0, Wh, bhp, E, hbuf, flags, out_h);
    head_kernel<<<BATCH, 64, 0, stream>>>(out_h, Wo, bo, out_lp);
    hipMemcpyAsync(out_st, st, (size_t)BH*sizeof(float), hipMemcpyDeviceToDevice, stream);
}

// Round 3
// 2652.785 us; speedup vs baseline: 1.0771x; 1.0771x over previous
//
#include <hip/hip_runtime.h>

#define T_STEPS 512
#define BATCH   256
#define DIM     1024
#define NOUT    5
#define BH      (BATCH*DIM)
#define TB      (T_STEPS*BATCH)

typedef short s16x8 __attribute__((ext_vector_type(8)));
typedef float f32x4 __attribute__((ext_vector_type(4)));
typedef unsigned int u32;
typedef unsigned short u16;
typedef u32 u32x4 __attribute__((ext_vector_type(4)));
typedef u32 u32x2 __attribute__((ext_vector_type(2)));

__device__ __forceinline__ u16 f2bf(float f) {
    union { float f; u32 u; } v; v.f = f;
    u32 r = v.u + 0x7FFFu + ((v.u >> 16) & 1u);   // RNE
    return (u16)(r >> 16);
}
__device__ __forceinline__ float bf2f(u16 u) {
    union { u32 u; float f; } v; v.u = ((u32)u) << 16;
    return v.f;
}
__device__ __forceinline__ s16x8 cvt8(float4 a, float4 b) {
    s16x8 v;
    v[0]=(short)f2bf(a.x); v[1]=(short)f2bf(a.y); v[2]=(short)f2bf(a.z); v[3]=(short)f2bf(a.w);
    v[4]=(short)f2bf(b.x); v[5]=(short)f2bf(b.y); v[6]=(short)f2bf(b.z); v[7]=(short)f2bf(b.w);
    return v;
}

// LLC-coherent (cross-XCD) ops: bypass L1+L2 via sc0 sc1.
__device__ __forceinline__ void ldg_cv16_issue(const u16* p, u32x4* dst) {
    asm volatile("global_load_dwordx4 %0, %1, off sc0 sc1"
                 : "=v"(*dst) : "v"(p) : "memory");
}
__device__ __forceinline__ void stg_cv8_u32(u16* p, u32x2 v) {
    asm volatile("global_store_dwordx2 %0, %1, off sc0 sc1"
                 :: "v"(p), "v"(v) : "memory");
}

// ---------------------------------------------------------------- convert fp32 -> bf16 (W_in)
__global__ __launch_bounds__(256) void cvt_kernel(const float* __restrict__ src,
                                                  u16* __restrict__ dst, int n4) {
    int i = blockIdx.x * 256 + threadIdx.x;
    if (i < n4) {
        float4 x = ((const float4*)src)[i];
        ushort4 o;
        o.x = f2bf(x.x); o.y = f2bf(x.y); o.z = f2bf(x.z); o.w = f2bf(x.w);
        ((ushort4*)dst)[i] = o;
    }
}

// ---------------------------------------------------------------- convert fp32 -> bf16 (X, 8/thread)
__global__ __launch_bounds__(256) void cvt_x(const float* __restrict__ src,
                                             u16* __restrict__ dst, int n8) {
    int i = blockIdx.x * 256 + threadIdx.x;
    if (i < n8) {
        float4 a = ((const float4*)src)[2*i];
        float4 b = ((const float4*)src)[2*i + 1];
        *(s16x8*)&dst[(size_t)i*8] = cvt8(a, b);
    }
}

// ---------------------------------------------------------------- Phase 1: E = Xb @ Wb^T + b_in
// Both operands bf16 staged via global_load_lds (XOR-pre-swizzled source).
// Epilogue staged through LDS for fully coalesced 16B stores.
__global__ __launch_bounds__(256, 2) void gemm_e_bf(
    const u16*   __restrict__ Xb,   // [131072][1024] bf16
    const u16*   __restrict__ Wb,   // [1024][1024] bf16 (row = out col, K contiguous)
    const float* __restrict__ b_in, // [1024]
    u16*         __restrict__ E)    // [131072][1024] bf16
{
    __shared__ u16 smem[2 * 128 * 64];   // sA | sB ; reused as 128x128 C-tile in epilogue
    u16* sA = smem;
    u16* sB = smem + 128 * 64;

    const int K = 1024;
    int tid  = threadIdx.x;
    int lane = tid & 63, wv = tid >> 6;
    int lm   = lane & 15, quad = lane >> 4;

    // XCD-team swizzle: all 8 bn-blocks of one bm share the A-tile via XCD L2.
    int bid = blockIdx.x;
    int xcd = bid & 7;
    int s   = bid >> 3;
    int bn  = s & 7;
    int bm  = (s >> 3) * 8 + xcd;

    int wm = wv >> 1, wn = wv & 1;

    float bias[4];
#pragma unroll
    for (int nt = 0; nt < 4; ++nt)
        bias[nt] = b_in[bn*128 + wn*64 + nt*16 + lm];

    f32x4 acc[4][4];
#pragma unroll
    for (int a = 0; a < 4; ++a)
#pragma unroll
        for (int b = 0; b < 4; ++b)
            acc[a][b] = (f32x4){0.f, 0.f, 0.f, 0.f};

    int colX  = (lane & 7) ^ (lane >> 3);   // source-chunk pre-swizzle
    int rowX0 = lane >> 3;

    for (int kk = 0; kk < K; kk += 64) {
#pragma unroll
        for (int i = 0; i < 4; ++i) {
            int q   = i*4 + wv;
            int row = q*8 + rowX0;
            const u16* gpB = Wb + (size_t)(bn*128 + row)*K + kk + colX*8;
            __builtin_amdgcn_global_load_lds(
                (const __attribute__((address_space(1))) void*)gpB,
                (__attribute__((address_space(3))) void*)(sB + q*512),
                16, 0, 0);
            const u16* gpA = Xb + (size_t)(bm*128 + row)*K + kk + colX*8;
            __builtin_amdgcn_global_load_lds(
                (const __attribute__((address_space(1))) void*)gpA,
                (__attribute__((address_space(3))) void*)(sA + q*512),
                16, 0, 0);
        }
        __syncthreads();
#pragma unroll
        for (int kc = 0; kc < 2; ++kc) {
            s16x8 af[4], bfr[4];
            int c8 = kc*4 + quad;
#pragma unroll
            for (int mt = 0; mt < 4; ++mt) {
                int row = wm*64 + mt*16 + lm;
                af[mt] = *(const s16x8*)&sA[row*64 + ((c8 ^ (row & 7)) * 8)];
            }
#pragma unroll
            for (int nt = 0; nt < 4; ++nt) {
                int row = wn*64 + nt*16 + lm;
                bfr[nt] = *(const s16x8*)&sB[row*64 + ((c8 ^ (row & 7)) * 8)];
            }
#pragma unroll
            for (int mt = 0; mt < 4; ++mt)
#pragma unroll
                for (int nt = 0; nt < 4; ++nt)
                    acc[mt][nt] = __builtin_amdgcn_mfma_f32_16x16x32_bf16(
                        af[mt], bfr[nt], acc[mt][nt], 0, 0, 0);
        }
        __syncthreads();
    }

    // ---- epilogue: C-tile through LDS, then coalesced 16B stores
#pragma unroll
    for (int mt = 0; mt < 4; ++mt)
#pragma unroll
        for (int nt = 0; nt < 4; ++nt)
#pragma unroll
            for (int i = 0; i < 4; ++i) {
                int row = wm*64 + mt*16 + quad*4 + i;
                int col = wn*64 + nt*16 + lm;
                smem[row*128 + col] = f2bf(acc[mt][nt][i] + bias[nt]);
            }
    __syncthreads();
#pragma unroll
    for (int sIt = 0; sIt < 8; ++sIt) {
        int flat = sIt*4096 + tid*16;          // byte offset into 32KB tile
        int row  = flat >> 8;                  // 256B per row (128 u16)
        int colb = flat & 255;                 // byte within row
        s16x8 v = *(const s16x8*)((const char*)smem + flat);
        *(s16x8*)&E[(size_t)(bm*128 + row)*1024 + bn*128 + colb/2] = v;
    }
}

// ---------------------------------------------------------------- Phase 1 fallback (fp32 X staged in-kernel)
#define PADA 88

__global__ __launch_bounds__(256, 2) void gemm_e(
    const float* __restrict__ X,
    const u16*   __restrict__ Wb,
    const float* __restrict__ b_in,
    u16*         __restrict__ E)
{
    __shared__ u16 sA[128 * PADA];
    __shared__ u16 sB[128 * 64];

    const int K = 1024;
    int tid  = threadIdx.x;
    int lane = tid & 63, wv = tid >> 6;
    int lm   = lane & 15, quad = lane >> 4;

    int bid = blockIdx.x;
    int xcd = bid & 7;
    int s   = bid >> 3;
    int bn  = s & 7;
    int bm  = (s >> 3) * 8 + xcd;

    int wm = wv >> 1, wn = wv & 1;

    float bias[4];
#pragma unroll
    for (int nt = 0; nt < 4; ++nt)
        bias[nt] = b_in[bn*128 + wn*64 + nt*16 + lm];

    f32x4 acc[4][4];
#pragma unroll
    for (int a = 0; a < 4; ++a)
#pragma unroll
        for (int b = 0; b < 4; ++b)
            acc[a][b] = (f32x4){0.f, 0.f, 0.f, 0.f};

    int colB  = (lane & 7) ^ (lane >> 3);
    int rowB0 = lane >> 3;

    for (int kk = 0; kk < K; kk += 64) {
#pragma unroll
        for (int i = 0; i < 4; ++i) {
            int q   = i*4 + wv;
            int row = q*8 + rowB0;
            const u16* gp = Wb + (size_t)(bn*128 + row)*K + kk + colB*8;
            __builtin_amdgcn_global_load_lds(
                (const __attribute__((address_space(1))) void*)gp,
                (__attribute__((address_space(3))) void*)(sB + q*512),
                16, 0, 0);
        }
#pragma unroll
        for (int p = 0; p < 4; ++p) {
            int row = (tid >> 3) + 32*p;
            int k8  = (tid & 7) * 8;
            const float* gp = X + (size_t)(bm*128 + row)*K + kk + k8;
            float4 x0 = ((const float4*)gp)[0];
            float4 x1 = ((const float4*)gp)[1];
            *(s16x8*)&sA[row*PADA + k8] = cvt8(x0, x1);
        }
        __syncthreads();
#pragma unroll
        for (int kc = 0; kc < 2; ++kc) {
            s16x8 af[4], bfr[4];
#pragma unroll
            for (int mt = 0; mt < 4; ++mt) {
                int row = wm*64 + mt*16 + lm;
                af[mt] = *(const s16x8*)&sA[row*PADA + kc*32 + quad*8];
            }
            int c8 = kc*4 + quad;
#pragma unroll
            for (int nt = 0; nt < 4; ++nt) {
                int row = wn*64 + nt*16 + lm;
                bfr[nt] = *(const s16x8*)&sB[row*64 + ((c8 ^ (row & 7)) * 8)];
            }
#pragma unroll
            for (int mt = 0; mt < 4; ++mt)
#pragma unroll
                for (int nt = 0; nt < 4; ++nt)
                    acc[mt][nt] = __builtin_amdgcn_mfma_f32_16x16x32_bf16(
                        af[mt], bfr[nt], acc[mt][nt], 0, 0, 0);
        }
        __syncthreads();
    }
#pragma unroll
    for (int mt = 0; mt < 4; ++mt)
#pragma unroll
        for (int nt = 0; nt < 4; ++nt)
#pragma unroll
            for (int i = 0; i < 4; ++i) {
                int row = bm*128 + wm*64 + mt*16 + quad*4 + i;
                int col = bn*128 + wn*64 + nt*16 + lm;
                E[(size_t)row*1024 + col] = f2bf(acc[mt][nt][i] + bias[nt]);
            }
}

// ---------------------------------------------------------------- Phase 2: recurrence
// FLAGLESS sync: sigmoid outputs are strictly positive, so every bf16's sign
// bit is free. Producers embed step-tag (t+1)&3 in the sign bits of each u32
// pair (bit0 -> low-half sign, bit1 -> high-half sign). Consumers spin
// RE-LOADING THE DATA ITSELF until all 64 values carry the expected tag —
// the data is the flag. No atomics, no flag lines, no store-ack in the chain.
// Ordering: each wave's per-step vmcnt(0) (the af wait) drains its own prior
// stores -> same-address store order holds -> tag mod 4 uniquely identifies
// h(t) vs h(t-2) (the only reachable residents; hbuf memset to tag-0 and the
// drain argument excludes older survivors). WAR on the double buffer: stores
// happen after the mid-step barrier, which joins 4 waves whose tag-verified
// reads cover all 16 producer WGs of the r-group (same proof as the flag
// version). LDS reduce double-buffered -> ONE barrier per step.
__global__ __launch_bounds__(256, 1) void rnn_phase2(
    const float* __restrict__ h0,   // [256][1024] fp32
    const float* __restrict__ Wh,   // [1024][1024] fp32 (row = out col)
    const float* __restrict__ bh,   // [1024]
    const u16*   __restrict__ E,    // [512][256][1024] bf16
    u16*         __restrict__ hbuf, // [2][256][1024] bf16 (sign-tagged)
    float*       __restrict__ hidden_out) // [256][1024] fp32
{
    __shared__ float red[2][4][16][68];
    int tid  = threadIdx.x;
    int lane = tid & 63, wv = tid >> 6;
    int lm   = lane & 15, quad = lane >> 4;
    int r    = blockIdx.x >> 4, c = blockIdx.x & 15;

    // --- persistent W_h fragments (one-time load, fp32 -> bf16)
    s16x8 wf[4][8];
#pragma unroll
    for (int ct = 0; ct < 4; ++ct)
#pragma unroll
        for (int kc = 0; kc < 8; ++kc) {
            int n = c*64 + ct*16 + lm;
            int k = wv*256 + kc*32 + quad*8;
            const float* p = Wh + (size_t)n*1024 + k;
            float4 x0 = ((const float4*)p)[0];
            float4 x1 = ((const float4*)p)[1];
            wf[ct][kc] = cvt8(x0, x1);
        }

    int m  = tid >> 4;          // reduce-phase row 0..15
    int n4 = (tid & 15) * 4;    // reduce-phase col base (of 64)
    float4 bh4 = *(const float4*)&bh[c*64 + n4];
    int rowA = r*16 + lm;
    size_t aoff = (size_t)rowA*1024 + wv*256 + quad*8;          // + kc*32
    size_t soff = (size_t)(r*16 + m)*1024 + c*64 + n4;          // store/E offset

    for (int t = 0; t < T_STEPS; ++t) {
        // E[t]: race-free phase-1 data, normal cached load issued BEFORE the
        // poll so its HBM latency overlaps the spin (drained by loop vmcnt(0)).
        ushort4 e4 = *(const ushort4*)&E[(size_t)t*BH + soff];

        u32x4 afu[8];
        if (t == 0) {
#pragma unroll
            for (int kc = 0; kc < 8; ++kc) {
                const float* p = h0 + aoff + kc*32;
                float4 x0 = ((const float4*)p)[0];
                float4 x1 = ((const float4*)p)[1];
                afu[kc] = __builtin_bit_cast(u32x4, cvt8(x0, x1));
            }
        } else {
            const u16* hb = hbuf + (size_t)(t & 1)*BH;
            u32 s2 = (u32)t & 3u;
            u32 expect = ((s2 & 1u) ? 0x8000u : 0u) | ((s2 & 2u) ? 0x80000000u : 0u);
            for (;;) {
#pragma unroll
                for (int kc = 0; kc < 8; ++kc)
                    ldg_cv16_issue(hb + aoff + kc*32, &afu[kc]);
                asm volatile("s_waitcnt vmcnt(0)"
                             : "+v"(afu[0]), "+v"(afu[1]), "+v"(afu[2]), "+v"(afu[3]),
                               "+v"(afu[4]), "+v"(afu[5]), "+v"(afu[6]), "+v"(afu[7])
                             :: "memory");
                u32x4 bad4 = (u32x4){0u, 0u, 0u, 0u};
#pragma unroll
                for (int kc = 0; kc < 8; ++kc)
                    bad4 |= (afu[kc] ^ expect) & 0x80008000u;
                u32 bad = bad4[0] | bad4[1] | bad4[2] | bad4[3];
                if (__all(bad == 0u)) break;
            }
            // strip tags (values are bit-identical after clearing sign bits)
#pragma unroll
            for (int kc = 0; kc < 8; ++kc)
                afu[kc] &= 0x7FFF7FFFu;
        }

        f32x4 acc[4];
#pragma unroll
        for (int ct = 0; ct < 4; ++ct) acc[ct] = (f32x4){0.f, 0.f, 0.f, 0.f};
#pragma unroll
        for (int kc = 0; kc < 8; ++kc) {
            s16x8 a = __builtin_bit_cast(s16x8, afu[kc]);
#pragma unroll
            for (int ct = 0; ct < 4; ++ct)
                acc[ct] = __builtin_amdgcn_mfma_f32_16x16x32_bf16(a, wf[ct][kc], acc[ct], 0, 0, 0);
        }

        // K-partial results -> LDS (double-buffered)
#pragma unroll
        for (int ct = 0; ct < 4; ++ct)
#pragma unroll
            for (int i = 0; i < 4; ++i)
                red[t & 1][wv][quad*4 + i][ct*16 + lm] = acc[ct][i];
        __syncthreads();   // the ONLY barrier per step

        // reduce 4 wave-partials + bias + e, sigmoid
        float4 p0 = *(const float4*)&red[t & 1][0][m][n4];
        float4 p1 = *(const float4*)&red[t & 1][1][m][n4];
        float4 p2 = *(const float4*)&red[t & 1][2][m][n4];
        float4 p3 = *(const float4*)&red[t & 1][3][m][n4];
        float4 sv;
        sv.x = p0.x + p1.x + p2.x + p3.x + bh4.x + bf2f(e4.x);
        sv.y = p0.y + p1.y + p2.y + p3.y + bh4.y + bf2f(e4.y);
        sv.z = p0.z + p1.z + p2.z + p3.z + bh4.z + bf2f(e4.z);
        sv.w = p0.w + p1.w + p2.w + p3.w + bh4.w + bf2f(e4.w);
        float4 h;
        h.x = 1.f / (1.f + __expf(-sv.x));
        h.y = 1.f / (1.f + __expf(-sv.y));
        h.z = 1.f / (1.f + __expf(-sv.z));
        h.w = 1.f / (1.f + __expf(-sv.w));

        if (t < T_STEPS - 1) {
            u32 s3   = (u32)(t + 1) & 3u;
            u32 mask = ((s3 & 1u) ? 0x8000u : 0u) | ((s3 & 2u) ? 0x80000000u : 0u);
            u32x2 st;
            st[0] = ((u32)f2bf(h.x) | ((u32)f2bf(h.y) << 16)) | mask;
            st[1] = ((u32)f2bf(h.z) | ((u32)f2bf(h.w) << 16)) | mask;
            // fire-and-forget LLC store; next step's vmcnt(0) provides the
            // same-address ordering drain.
            stg_cv8_u32(&hbuf[(size_t)((t + 1) & 1)*BH + soff], st);
        } else {
            *(float4*)&hidden_out[soff] = h;
        }
    }
}

// ---------------------------------------------------------------- Phase 3: log_softmax(h W_o^T + b_o)
__global__ __launch_bounds__(64) void head_kernel(const float* __restrict__ h,
                                                  const float* __restrict__ Wo,
                                                  const float* __restrict__ bo,
                                                  float* __restrict__ out)
{
    int b = blockIdx.x, l = threadIdx.x;
    float a0 = 0.f, a1 = 0.f, a2 = 0.f, a3 = 0.f, a4 = 0.f;
    for (int k = l; k < DIM; k += 64) {
        float hv = h[b*DIM + k];
        a0 += hv * Wo[0*DIM + k];
        a1 += hv * Wo[1*DIM + k];
        a2 += hv * Wo[2*DIM + k];
        a3 += hv * Wo[3*DIM + k];
        a4 += hv * Wo[4*DIM + k];
    }
#pragma unroll
    for (int off = 32; off >= 1; off >>= 1) {
        a0 += __shfl_down(a0, off);
        a1 += __shfl_down(a1, off);
        a2 += __shfl_down(a2, off);
        a3 += __shfl_down(a3, off);
        a4 += __shfl_down(a4, off);
    }
    if (l == 0) {
        float v[5] = {a0 + bo[0], a1 + bo[1], a2 + bo[2], a3 + bo[3], a4 + bo[4]};
        float mx = v[0];
#pragma unroll
        for (int o = 1; o < 5; ++o) mx = fmaxf(mx, v[o]);
        float sum = 0.f;
#pragma unroll
        for (int o = 0; o < 5; ++o) sum += __expf(v[o] - mx);
        float lse = mx + __logf(sum);
#pragma unroll
        for (int o = 0; o < 5; ++o) out[b*NOUT + o] = v[o] - lse;
    }
}

// ---------------------------------------------------------------- launch
extern "C" void kernel_launch(void* const* d_in, const int* in_sizes, int n_in,
                              void* d_out, int out_size, void* d_ws, size_t ws_size,
                              hipStream_t stream)
{
    const float* X   = (const float*)d_in[0];
    const float* h0  = (const float*)d_in[1];
    const float* st  = (const float*)d_in[2];
    const float* Win = (const float*)d_in[3];
    const float* bin = (const float*)d_in[4];
    const float* Wh  = (const float*)d_in[5];
    const float* bhp = (const float*)d_in[6];
    const float* Wo  = (const float*)d_in[7];
    const float* bo  = (const float*)d_in[8];

    char*  ws      = (char*)d_ws;
    size_t off_hb  = 32768;
    size_t off_wb  = off_hb + (size_t)2*BH*2;
    size_t off_e   = off_wb + (size_t)DIM*DIM*2;
    size_t off_xb  = off_e + (size_t)TB*DIM*2;
    size_t need_bf = off_xb + (size_t)TB*DIM*2;

    u16* hbuf  = (u16*)(ws + off_hb);
    u16* Wbf   = (u16*)(ws + off_wb);
    u16* E     = (u16*)(ws + off_e);
    u16* Xbf   = (u16*)(ws + off_xb);

    float* out_lp = (float*)d_out;          // [256][5]
    float* out_h  = out_lp + BATCH*NOUT;    // [256][1024]
    float* out_st = out_h + BH;             // [256][1024]

    // hbuf must be tag-0 (sign bits clear) at start: memset once per launch.
    hipMemsetAsync(hbuf, 0, (size_t)2*BH*2, stream);
    cvt_kernel<<<(DIM*DIM/4 + 255)/256, 256, 0, stream>>>(Win, Wbf, DIM*DIM/4);

    if (ws_size >= need_bf) {
        cvt_x<<<(TB*DIM/8)/256, 256, 0, stream>>>(X, Xbf, TB*DIM/8);
        gemm_e_bf<<<(TB/128)*8, 256, 0, stream>>>(Xbf, Wbf, bin, E);
    } else {
        gemm_e<<<(TB/128)*8, 256, 0, stream>>>(X, Wbf, bin, E);
    }

    rnn_phase2<<<256, 256, 0, stream>>>(h0, Wh, bhp, E, hbuf, out_h);
    head_kernel<<<BATCH, 64, 0, stream>>>(out_h, Wo, bo, out_lp);
    hipMemcpyAsync(out_st, st, (size_t)BH*sizeof(float), hipMemcpyDeviceToDevice, stream);
}

// Round 4
// 2607.108 us; speedup vs baseline: 1.0960x; 1.0175x over previous
//
#include <hip/hip_runtime.h>

#define T_STEPS 512
#define BATCH   256
#define DIM     1024
#define NOUT    5
#define BH      (BATCH*DIM)
#define TB      (T_STEPS*BATCH)
#define PADA    88
#define NWRK    256

typedef short s16x8 __attribute__((ext_vector_type(8)));
typedef float f32x4 __attribute__((ext_vector_type(4)));
typedef unsigned int u32;
typedef unsigned short u16;
typedef u32 u32x4 __attribute__((ext_vector_type(4)));
typedef u32 u32x2 __attribute__((ext_vector_type(2)));

__device__ __forceinline__ u16 f2bf(float f) {
    union { float f; u32 u; } v; v.f = f;
    u32 r = v.u + 0x7FFFu + ((v.u >> 16) & 1u);   // RNE
    return (u16)(r >> 16);
}
__device__ __forceinline__ float bf2f(u16 u) {
    union { u32 u; float f; } v; v.u = ((u32)u) << 16;
    return v.f;
}
__device__ __forceinline__ s16x8 cvt8(float4 a, float4 b) {
    s16x8 v;
    v[0]=(short)f2bf(a.x); v[1]=(short)f2bf(a.y); v[2]=(short)f2bf(a.z); v[3]=(short)f2bf(a.w);
    v[4]=(short)f2bf(b.x); v[5]=(short)f2bf(b.y); v[6]=(short)f2bf(b.z); v[7]=(short)f2bf(b.w);
    return v;
}

// LLC-coherent (cross-XCD) ops: bypass L1+L2 via sc0 sc1.
__device__ __forceinline__ void ldg_cv16_issue(const u16* p, u32x4* dst) {
    asm volatile("global_load_dwordx4 %0, %1, off sc0 sc1"
                 : "=v"(*dst) : "v"(p) : "memory");
}
__device__ __forceinline__ void ldg_cv8_issue(const u16* p, u32x2* dst) {
    asm volatile("global_load_dwordx2 %0, %1, off sc0 sc1"
                 : "=v"(*dst) : "v"(p) : "memory");
}
__device__ __forceinline__ void ldg_cv4_issue(const u32* p, u32* dst) {
    asm volatile("global_load_dword %0, %1, off sc0 sc1"
                 : "=v"(*dst) : "v"(p) : "memory");
}
__device__ __forceinline__ void stg_cv8_u32(u16* p, u32x2 v) {
    asm volatile("global_store_dwordx2 %0, %1, off sc0 sc1"
                 :: "v"(p), "v"(v) : "memory");
}
__device__ __forceinline__ void stg_cv16(u16* p, s16x8 v) {
    asm volatile("global_store_dwordx4 %0, %1, off sc0 sc1"
                 :: "v"(p), "v"(v) : "memory");
}
__device__ __forceinline__ void wait_vm0() {
    asm volatile("s_waitcnt vmcnt(0)" ::: "memory");
}

// ---------------------------------------------------------------- convert fp32 -> bf16 (W_in)
__global__ __launch_bounds__(256) void cvt_kernel(const float* __restrict__ src,
                                                  u16* __restrict__ dst, int n4) {
    int i = blockIdx.x * 256 + threadIdx.x;
    if (i < n4) {
        float4 x = ((const float4*)src)[i];
        ushort4 o;
        o.x = f2bf(x.x); o.y = f2bf(x.y); o.z = f2bf(x.z); o.w = f2bf(x.w);
        ((ushort4*)dst)[i] = o;
    }
}

// ---------------------------------------------------------------- fused producer/consumer
// blocks 0..255   : PRODUCERS. Loop j=0..31 over E-tiles (bm = 32j + xcd*4 + v,
//                   bn fixed per worker); 8 bn-sharers of each bm have the same
//                   bid&7 (same XCD) for L2 A-tile reuse. E stored sc0 sc1,
//                   acked, then cnt[bm>>1] incremented (16 tiles per t).
// blocks 256..511 : RNN consumers (R3 flagless tag sync), gated on cnt[t] with
//                   one-step lookahead (cnt[t+1] sampled during step t's poll).
// Co-residency: LDS 38912 B/block, VGPR capped by __launch_bounds__(256,2)
//   -> 2 blocks/CU, all 512 resident. Deadlock-free even if not: producers
//   depend on nothing and retire, freeing slots.
__global__ __launch_bounds__(256, 2) void rnn_fused(
    const float* __restrict__ X,    // [131072][1024] fp32
    const u16*   __restrict__ Wb,   // [1024][1024] bf16
    const float* __restrict__ b_in, // [1024]
    u16*         __restrict__ E,    // [512][256][1024] bf16
    const float* __restrict__ h0,   // [256][1024] fp32
    const float* __restrict__ Wh,   // [1024][1024] fp32
    const float* __restrict__ bh,   // [1024]
    u16*         __restrict__ hbuf, // [2][256][1024] bf16 (sign-tagged)
    u32*         __restrict__ cnt,  // [512] per-t tile counters
    float*       __restrict__ hidden_out) // [256][1024] fp32
{
    __shared__ __align__(16) char lds_raw[39936];
    int bid  = blockIdx.x;
    int tid  = threadIdx.x;
    int lane = tid & 63, wv = tid >> 6;
    int lm   = lane & 15, quad = lane >> 4;

    if (bid < NWRK) {
        // ======================= PRODUCER =======================
        u16* sA = (u16*)lds_raw;                      // 128 x PADA
        u16* sB = (u16*)(lds_raw + 128*PADA*2);       // 128 x 64
        const int K = 1024;
        int w   = bid;
        int xcd = w & 7;
        int uu  = w >> 3;
        int vq  = uu & 3;
        int bn  = uu >> 2;
        int wm  = wv >> 1, wn = wv & 1;
        int colB  = (lane & 7) ^ (lane >> 3);
        int rowB0 = lane >> 3;

        float bias[4];
#pragma unroll
        for (int nt = 0; nt < 4; ++nt)
            bias[nt] = b_in[bn*128 + wn*64 + nt*16 + lm];

        for (int j = 0; j < 32; ++j) {
            int bm = j*32 + xcd*4 + vq;

            f32x4 acc[4][4];
#pragma unroll
            for (int a = 0; a < 4; ++a)
#pragma unroll
                for (int b = 0; b < 4; ++b)
                    acc[a][b] = (f32x4){0.f, 0.f, 0.f, 0.f};

            for (int kk = 0; kk < K; kk += 64) {
#pragma unroll
                for (int i = 0; i < 4; ++i) {
                    int q   = i*4 + wv;
                    int row = q*8 + rowB0;
                    const u16* gp = Wb + (size_t)(bn*128 + row)*K + kk + colB*8;
                    __builtin_amdgcn_global_load_lds(
                        (const __attribute__((address_space(1))) void*)gp,
                        (__attribute__((address_space(3))) void*)(sB + q*512),
                        16, 0, 0);
                }
#pragma unroll
                for (int p = 0; p < 4; ++p) {
                    int row = (tid >> 3) + 32*p;
                    int k8  = (tid & 7) * 8;
                    const float* gp = X + (size_t)(bm*128 + row)*K + kk + k8;
                    float4 x0 = ((const float4*)gp)[0];
                    float4 x1 = ((const float4*)gp)[1];
                    *(s16x8*)&sA[row*PADA + k8] = cvt8(x0, x1);
                }
                __syncthreads();
#pragma unroll
                for (int kc = 0; kc < 2; ++kc) {
                    s16x8 af[4], bfr[4];
#pragma unroll
                    for (int mt = 0; mt < 4; ++mt) {
                        int row = wm*64 + mt*16 + lm;
                        af[mt] = *(const s16x8*)&sA[row*PADA + kc*32 + quad*8];
                    }
                    int c8 = kc*4 + quad;
#pragma unroll
                    for (int nt = 0; nt < 4; ++nt) {
                        int row = wn*64 + nt*16 + lm;
                        bfr[nt] = *(const s16x8*)&sB[row*64 + ((c8 ^ (row & 7)) * 8)];
                    }
#pragma unroll
                    for (int mt = 0; mt < 4; ++mt)
#pragma unroll
                        for (int nt = 0; nt < 4; ++nt)
                            acc[mt][nt] = __builtin_amdgcn_mfma_f32_16x16x32_bf16(
                                af[mt], bfr[nt], acc[mt][nt], 0, 0, 0);
                }
                __syncthreads();
            }

            // epilogue: C-tile (128x128 bf16, 32 KB) through LDS, coherent 16B stores
            u16* csm = (u16*)lds_raw;
#pragma unroll
            for (int mt = 0; mt < 4; ++mt)
#pragma unroll
                for (int nt = 0; nt < 4; ++nt)
#pragma unroll
                    for (int i = 0; i < 4; ++i) {
                        int row = wm*64 + mt*16 + quad*4 + i;
                        int col = wn*64 + nt*16 + lm;
                        csm[row*128 + col] = f2bf(acc[mt][nt][i] + bias[nt]);
                    }
            __syncthreads();
#pragma unroll
            for (int sIt = 0; sIt < 8; ++sIt) {
                int flat = sIt*4096 + tid*16;
                int row  = flat >> 8;
                int colb = flat & 255;
                s16x8 vv = *(const s16x8*)(lds_raw + flat);
                stg_cv16(&E[(size_t)(bm*128 + row)*1024 + bn*128 + colb/2], vv);
            }
            wait_vm0();        // own E stores acked at coherence point
            __syncthreads();   // ALL threads acked before publish; csm reads done
            if (tid == 0)
                __hip_atomic_fetch_add(cnt + (bm >> 1), 1u,
                                       __ATOMIC_RELAXED, __HIP_MEMORY_SCOPE_AGENT);
        }
        return;
    }

    // ======================= RNN CONSUMER =======================
    typedef float redT[4][16][68];
    redT* red = (redT*)lds_raw;          // [2] double-buffered reduce array
    int rb = bid - NWRK;
    int r  = rb >> 4, c = rb & 15;

    // persistent W_h fragments (one-time load, fp32 -> bf16)
    s16x8 wf[4][8];
#pragma unroll
    for (int ct = 0; ct < 4; ++ct)
#pragma unroll
        for (int kc = 0; kc < 8; ++kc) {
            int n = c*64 + ct*16 + lm;
            int k = wv*256 + kc*32 + quad*8;
            const float* p = Wh + (size_t)n*1024 + k;
            float4 x0 = ((const float4*)p)[0];
            float4 x1 = ((const float4*)p)[1];
            wf[ct][kc] = cvt8(x0, x1);
        }

    int m   = tid >> 4;
    int n4q = (tid & 15) * 4;
    float4 bh4 = *(const float4*)&bh[c*64 + n4q];
    int rowA = r*16 + lm;
    size_t aoff = (size_t)rowA*1024 + wv*256 + quad*8;
    size_t soff = (size_t)(r*16 + m)*1024 + c*64 + n4q;

    // gate: E[0] and E[1] ready (cnt confirmed BEFORE any e4 load issues)
    if (tid == 0) {
        for (;;) {
            u32 a, b;
            ldg_cv4_issue(cnt + 0, &a);
            ldg_cv4_issue(cnt + 1, &b);
            asm volatile("s_waitcnt vmcnt(0)" : "+v"(a), "+v"(b) :: "memory");
            if (a >= 16u && b >= 16u) break;
            __builtin_amdgcn_s_sleep(8);
        }
    }
    __syncthreads();

    bool oknext = true;   // cnt[1] confirmed above
    for (int t = 0; t < T_STEPS; ++t) {
        u32x2 e4u;
        u32x4 afu[8];
        if (t == 0) {
            ldg_cv8_issue(E + soff, &e4u);
#pragma unroll
            for (int kc = 0; kc < 8; ++kc) {
                const float* p = h0 + aoff + kc*32;
                float4 x0 = ((const float4*)p)[0];
                float4 x1 = ((const float4*)p)[1];
                afu[kc] = __builtin_bit_cast(u32x4, cvt8(x0, x1));
            }
            asm volatile("s_waitcnt vmcnt(0)" : "+v"(e4u) :: "memory");
        } else {
            const u16* hb = hbuf + (size_t)(t & 1)*BH;
            const u16* ep = E + (size_t)t*BH + soff;
            u32 s2 = (u32)t & 3u;
            u32 expect = ((s2 & 1u) ? 0x8000u : 0u) | ((s2 & 2u) ? 0x80000000u : 0u);
            bool okc = oknext;   // cnt[t] seen >=16 in a STRICTLY EARLIER round
            bool okn = false;
            for (;;) {
#pragma unroll
                for (int kc = 0; kc < 8; ++kc)
                    ldg_cv16_issue(hb + aoff + kc*32, &afu[kc]);
                u32 cN, cC;
                ldg_cv8_issue(ep, &e4u);
                ldg_cv4_issue(cnt + t + 1, &cN);
                ldg_cv4_issue(cnt + t,     &cC);
                asm volatile("s_waitcnt vmcnt(0)"
                             : "+v"(afu[0]), "+v"(afu[1]), "+v"(afu[2]), "+v"(afu[3]),
                               "+v"(afu[4]), "+v"(afu[5]), "+v"(afu[6]), "+v"(afu[7]),
                               "+v"(e4u), "+v"(cN), "+v"(cC)
                             :: "memory");
                bool use = okc;           // e4 from THIS round valid only if cnt[t]
                okn = okn | (cN >= 16u);  //   was confirmed before it was issued
                okc = okc | (cC >= 16u);
                u32x4 bad4 = (u32x4){0u, 0u, 0u, 0u};
#pragma unroll
                for (int kc = 0; kc < 8; ++kc)
                    bad4 |= (afu[kc] ^ expect) & 0x80008000u;
                u32 bad = bad4[0] | bad4[1] | bad4[2] | bad4[3];
                if (use && __all(bad == 0u)) break;
            }
            oknext = okn;
#pragma unroll
            for (int kc = 0; kc < 8; ++kc)
                afu[kc] &= 0x7FFF7FFFu;   // strip tags (bit-identical values)
        }

        f32x4 acc[4];
#pragma unroll
        for (int ct = 0; ct < 4; ++ct) acc[ct] = (f32x4){0.f, 0.f, 0.f, 0.f};
#pragma unroll
        for (int kc = 0; kc < 8; ++kc) {
            s16x8 a = __builtin_bit_cast(s16x8, afu[kc]);
#pragma unroll
            for (int ct = 0; ct < 4; ++ct)
                acc[ct] = __builtin_amdgcn_mfma_f32_16x16x32_bf16(a, wf[ct][kc], acc[ct], 0, 0, 0);
        }

#pragma unroll
        for (int ct = 0; ct < 4; ++ct)
#pragma unroll
            for (int i = 0; i < 4; ++i)
                red[t & 1][wv][quad*4 + i][ct*16 + lm] = acc[ct][i];
        __syncthreads();   // the ONLY barrier per step

        float4 p0 = *(const float4*)&red[t & 1][0][m][n4q];
        float4 p1 = *(const float4*)&red[t & 1][1][m][n4q];
        float4 p2 = *(const float4*)&red[t & 1][2][m][n4q];
        float4 p3 = *(const float4*)&red[t & 1][3][m][n4q];
        float4 sv;
        sv.x = p0.x + p1.x + p2.x + p3.x + bh4.x + bf2f((u16)(e4u[0] & 0xFFFFu));
        sv.y = p0.y + p1.y + p2.y + p3.y + bh4.y + bf2f((u16)(e4u[0] >> 16));
        sv.z = p0.z + p1.z + p2.z + p3.z + bh4.z + bf2f((u16)(e4u[1] & 0xFFFFu));
        sv.w = p0.w + p1.w + p2.w + p3.w + bh4.w + bf2f((u16)(e4u[1] >> 16));
        float4 h;
        h.x = 1.f / (1.f + __expf(-sv.x));
        h.y = 1.f / (1.f + __expf(-sv.y));
        h.z = 1.f / (1.f + __expf(-sv.z));
        h.w = 1.f / (1.f + __expf(-sv.w));

        if (t < T_STEPS - 1) {
            u32 s3   = (u32)(t + 1) & 3u;
            u32 mask = ((s3 & 1u) ? 0x8000u : 0u) | ((s3 & 2u) ? 0x80000000u : 0u);
            u32x2 st;
            st[0] = ((u32)f2bf(h.x) | ((u32)f2bf(h.y) << 16)) | mask;
            st[1] = ((u32)f2bf(h.z) | ((u32)f2bf(h.w) << 16)) | mask;
            stg_cv8_u32(&hbuf[(size_t)((t + 1) & 1)*BH + soff], st);
        } else {
            *(float4*)&hidden_out[soff] = h;
        }
    }
}

// ---------------------------------------------------------------- Phase 3: log_softmax(h W_o^T + b_o)
__global__ __launch_bounds__(64) void head_kernel(const float* __restrict__ h,
                                                  const float* __restrict__ Wo,
                                                  const float* __restrict__ bo,
                                                  float* __restrict__ out)
{
    int b = blockIdx.x, l = threadIdx.x;
    float a0 = 0.f, a1 = 0.f, a2 = 0.f, a3 = 0.f, a4 = 0.f;
    for (int k = l; k < DIM; k += 64) {
        float hv = h[b*DIM + k];
        a0 += hv * Wo[0*DIM + k];
        a1 += hv * Wo[1*DIM + k];
        a2 += hv * Wo[2*DIM + k];
        a3 += hv * Wo[3*DIM + k];
        a4 += hv * Wo[4*DIM + k];
    }
#pragma unroll
    for (int off = 32; off >= 1; off >>= 1) {
        a0 += __shfl_down(a0, off);
        a1 += __shfl_down(a1, off);
        a2 += __shfl_down(a2, off);
        a3 += __shfl_down(a3, off);
        a4 += __shfl_down(a4, off);
    }
    if (l == 0) {
        float v[5] = {a0 + bo[0], a1 + bo[1], a2 + bo[2], a3 + bo[3], a4 + bo[4]};
        float mx = v[0];
#pragma unroll
        for (int o = 1; o < 5; ++o) mx = fmaxf(mx, v[o]);
        float sum = 0.f;
#pragma unroll
        for (int o = 0; o < 5; ++o) sum += __expf(v[o] - mx);
        float lse = mx + __logf(sum);
#pragma unroll
        for (int o = 0; o < 5; ++o) out[b*NOUT + o] = v[o] - lse;
    }
}

// ---------------------------------------------------------------- launch
extern "C" void kernel_launch(void* const* d_in, const int* in_sizes, int n_in,
                              void* d_out, int out_size, void* d_ws, size_t ws_size,
                              hipStream_t stream)
{
    const float* X   = (const float*)d_in[0];
    const float* h0  = (const float*)d_in[1];
    const float* st  = (const float*)d_in[2];
    const float* Win = (const float*)d_in[3];
    const float* bin = (const float*)d_in[4];
    const float* Wh  = (const float*)d_in[5];
    const float* bhp = (const float*)d_in[6];
    const float* Wo  = (const float*)d_in[7];
    const float* bo  = (const float*)d_in[8];

    char*  ws     = (char*)d_ws;
    size_t off_hb = 32768;
    size_t off_wb = off_hb + (size_t)2*BH*2;
    size_t off_e  = off_wb + (size_t)DIM*DIM*2;

    u32* cnt  = (u32*)ws;                 // 512 counters (within 32 KB zone)
    u16* hbuf = (u16*)(ws + off_hb);
    u16* Wbf  = (u16*)(ws + off_wb);
    u16* E    = (u16*)(ws + off_e);

    float* out_lp = (float*)d_out;          // [256][5]
    float* out_h  = out_lp + BATCH*NOUT;    // [256][1024]
    float* out_st = out_h + BH;             // [256][1024]

    hipMemsetAsync(ws, 0, 32768, stream);                 // cnt zone
    hipMemsetAsync(hbuf, 0, (size_t)2*BH*2, stream);      // tag-0 h buffers
    cvt_kernel<<<(DIM*DIM/4 + 255)/256, 256, 0, stream>>>(Win, Wbf, DIM*DIM/4);

    rnn_fused<<<512, 256, 0, stream>>>(X, Wbf, bin, E, h0, Wh, bhp, hbuf, cnt, out_h);

    head_kernel<<<BATCH, 64, 0, stream>>>(out_h, Wo, bo, out_lp);
    hipMemcpyAsync(out_st, st, (size_t)BH*sizeof(float), hipMemcpyDeviceToDevice, stream);
}